// Round 3
// baseline (164.728 us; speedup 1.0000x reference)
//
#include <hip/hip_runtime.h>
#include <math.h>

#define BATCH 32
#define HH 512
#define WW 512
#define TH 16                  // output rows per block
#define HALO 2
#define SRH (TH + 2*HALO)      // 20 staged rows
#define NDW (WW / 4)           // 128 dwords per row (u8-packed)
#define CSTRIDE 132            // csum row stride in dwords (1 pad + 128 + 1 pad + 2 slack)
#define NPIX ((float)BATCH * HH * WW)
#define HW (HH * WW)
#define NBLK (BATCH * (HH / TH))   // 1024

// ws layout (floats), zeroed by a 512B memset every launch:
//   ws[0..31]   per-image inter
//   ws[32..63]  per-image sum_bp
//   ws[64..95]  per-image sum_bt
//   ws[96] ce   ws[97] valid_cnt   ws[98] focal
//   ws[100]     (as uint) block-done counter
// All accumulation is device-scope atomic; last block computes out[0].

__global__ __launch_bounds__(256, 4) void bel_main_kernel(
        const float* __restrict__ pred,
        const int*   __restrict__ target,
        float*       __restrict__ ws,
        float*       __restrict__ out) {
    __shared__ unsigned int t8[SRH][NDW];      // target, 1 byte/pixel
    __shared__ unsigned int csum[TH][CSTRIDE]; // vertical 5-sums, packed u8
    __shared__ float red[6][4];
    __shared__ int isLast;

    const int tid = threadIdx.x;
    const int bid = blockIdx.x;
    const int b   = bid >> 5;          // image
    const int ty  = bid & 31;          // row-tile
    const int y0  = ty * TH;
    const size_t tb = (size_t)b * HW;

    // zero the horizontal pad dwords of csum (left=0, right=NDW+1)
    if (tid < 2 * TH) {
        int rr = tid >> 1;
        csum[rr][(tid & 1) ? (NDW + 1) : 0] = 0u;
    }

    // ---- stage 20 rows of target as packed u8 (zero rows outside image) ----
    #pragma unroll
    for (int it = 0; it < (SRH * NDW) / 256; ++it) {   // 10 iters
        const int i  = tid + 256 * it;
        const int r  = i >> 7;
        const int c4 = i & 127;
        const int gy = y0 - HALO + r;
        unsigned int packed = 0u;
        if ((unsigned)gy < (unsigned)HH) {
            const int4 v = *(const int4*)(target + tb + ((size_t)gy << 9) + (c4 << 2));
            packed = (unsigned)v.x | ((unsigned)v.y << 8)
                   | ((unsigned)v.z << 16) | ((unsigned)v.w << 24);
        }
        t8[r][c4] = packed;
    }
    __syncthreads();

    // ---- vertical 5-sum (packed u8 adds; max byte value 5, no carry) ----
    #pragma unroll
    for (int it = 0; it < (TH * NDW) / 256; ++it) {    // 8 iters
        const int j = tid + 256 * it;
        const int r = j >> 7;
        const int c = j & 127;
        csum[r][c + 1] = t8[r][c] + t8[r+1][c] + t8[r+2][c]
                       + t8[r+3][c] + t8[r+4][c];
    }
    __syncthreads();

    // ---- batched pred prefetch: 16 float4 loads in flight per thread ----
    // (kept AFTER the barriers: staging registers are dead here, so the 64
    //  VGPRs of F0/F1 fit under the 128-VGPR launch_bounds cap — hoisting
    //  them earlier spilled to scratch and cost +7us, round-1 post-mortem)
    const float4* __restrict__ pr0 = (const float4*)(pred + tb * 2);
    const float4* __restrict__ pr1 = (const float4*)(pred + tb * 2 + HW);
    const int base4 = (y0 << 7) + tid;   // float4 index of this thread's slot 0

    float4 F0[8], F1[8];
    #pragma unroll
    for (int it = 0; it < 8; ++it) F0[it] = pr0[base4 + 256 * it];
    #pragma unroll
    for (int it = 0; it < 8; ++it) F1[it] = pr1[base4 + 256 * it];

    float ce_acc = 0.f, cnt_acc = 0.f, focal_acc = 0.f;
    float inter_acc = 0.f, bp_acc = 0.f, bt_acc = 0.f;

    const unsigned long long M5 = 0xFFFFFFFFFFull;      // 5 bytes
    const unsigned long long ALL5 = 0x0505050505ull;    // box sum == 25

    const int g  = tid & 127;          // loop-invariant column group
    const int rb = tid >> 7;           // 0 or 1

    #pragma unroll
    for (int it = 0; it < 8; ++it) {
        const int r = rb + 2 * it;

        const float4 f0 = F0[it];
        const float4 f1 = F1[it];

        const unsigned int L = csum[r][g];
        const unsigned int M = csum[r][g + 1];
        const unsigned int R = csum[r][g + 2];
        const unsigned int tdw = t8[r + HALO][g];

        const unsigned long long lo  = (unsigned long long)L | ((unsigned long long)M << 32);
        const unsigned long long mid = (unsigned long long)M | ((unsigned long long)R << 32);

        #pragma unroll
        for (int i = 0; i < 4; ++i) {
            unsigned long long w;
            if      (i == 0) w = (lo  >> 16) & M5;
            else if (i == 1) w = (lo  >> 24) & M5;
            else if (i == 2) w =  mid        & M5;
            else             w = (mid >>  8) & M5;
            const float bm = (w != 0ull && w != ALL5) ? 1.0f : 0.0f;

            const unsigned int tv = (tdw >> (8 * i)) & 0xFFu;

            const float p0 = (i == 0) ? f0.x : (i == 1) ? f0.y : (i == 2) ? f0.z : f0.w;
            const float p1 = (i == 0) ? f1.x : (i == 1) ? f1.y : (i == 2) ? f1.z : f1.w;

            const float d  = p1 - p0;
            const float e  = __expf(-fabsf(d));
            const float rz = 1.0f / (1.0f + e);
            const float pmin = e * rz;
            const float prob1 = (d >= 0.0f) ? rz : pmin;
            const float pt = tv ? prob1 : (1.0f - prob1);
            const float ce = -__logf(pt);

            const float valid = (tv != 250u) ? 1.0f : 0.0f;
            ce_acc  += ce * valid;
            cnt_acc += valid;

            const float omp = 1.0f - pt;
            focal_acc += omp * omp * ce;                // *0.25 folded at the end

            const float bp = prob1 * bm;
            const float bt = (float)tv * bm;
            inter_acc += bp * bt;
            bp_acc    += bp;
            bt_acc    += bt;
        }
    }

    // ---- block reduction ----
    float vals[6] = {ce_acc, cnt_acc, focal_acc * 0.25f, inter_acc, bp_acc, bt_acc};
    #pragma unroll
    for (int jj = 0; jj < 6; ++jj) {
        float v = vals[jj];
        #pragma unroll
        for (int off = 32; off > 0; off >>= 1)
            v += __shfl_down(v, off, 64);
        vals[jj] = v;
    }
    const int wave = tid >> 6;
    const int lane = tid & 63;
    if (lane == 0) {
        #pragma unroll
        for (int jj = 0; jj < 6; ++jj) red[jj][wave] = vals[jj];
    }
    __syncthreads();

    // ---- device-scope accumulate + last-block finalize ----
    if (tid == 0) {
        const float s_ce    = red[0][0] + red[0][1] + red[0][2] + red[0][3];
        const float s_cnt   = red[1][0] + red[1][1] + red[1][2] + red[1][3];
        const float s_focal = red[2][0] + red[2][1] + red[2][2] + red[2][3];
        const float s_inter = red[3][0] + red[3][1] + red[3][2] + red[3][3];
        const float s_bp    = red[4][0] + red[4][1] + red[4][2] + red[4][3];
        const float s_bt    = red[5][0] + red[5][1] + red[5][2] + red[5][3];

        atomicAdd(&ws[b],        s_inter);
        atomicAdd(&ws[32 + b],   s_bp);
        atomicAdd(&ws[64 + b],   s_bt);
        atomicAdd(&ws[96],       s_ce);
        atomicAdd(&ws[97],       s_cnt);
        atomicAdd(&ws[98],       s_focal);

        __threadfence();   // release: value atomics ordered before counter
        unsigned int old = atomicAdd((unsigned int*)&ws[100], 1u);
        isLast = (old == (unsigned int)(NBLK - 1)) ? 1 : 0;
    }
    __syncthreads();

    if (isLast) {
        __threadfence();   // acquire side
        if (tid < BATCH) {
            const float inter = __hip_atomic_load(&ws[tid],      __ATOMIC_RELAXED, __HIP_MEMORY_SCOPE_AGENT);
            const float sbp   = __hip_atomic_load(&ws[32 + tid], __ATOMIC_RELAXED, __HIP_MEMORY_SCOPE_AGENT);
            const float sbt   = __hip_atomic_load(&ws[64 + tid], __ATOMIC_RELAXED, __HIP_MEMORY_SCOPE_AGENT);
            float dc = 2.0f * inter / (sbp + sbt + 1e-8f);
            #pragma unroll
            for (int off = 16; off > 0; off >>= 1)
                dc += __shfl_down(dc, off, 32);
            if (tid == 0) {
                const float ce  = __hip_atomic_load(&ws[96], __ATOMIC_RELAXED, __HIP_MEMORY_SCOPE_AGENT);
                const float cnt = __hip_atomic_load(&ws[97], __ATOMIC_RELAXED, __HIP_MEMORY_SCOPE_AGENT);
                const float foc = __hip_atomic_load(&ws[98], __ATOMIC_RELAXED, __HIP_MEMORY_SCOPE_AGENT);
                const float ce_loss = ce / fmaxf(cnt, 1.0f);
                const float focal   = foc / NPIX;
                const float bdice   = 1.0f - dc / (float)BATCH;
                out[0] = ce_loss + focal + bdice;   // BOUNDARY_W = 1.0
            }
        }
    }
}

extern "C" void kernel_launch(void* const* d_in, const int* in_sizes, int n_in,
                              void* d_out, int out_size, void* d_ws, size_t ws_size,
                              hipStream_t stream) {
    const float* pred   = (const float*)d_in[0];
    const int*   target = (const int*)d_in[1];
    float* ws  = (float*)d_ws;
    float* out = (float*)d_out;

    // zero accumulators + counter (128 floats); graph-capturable memset node
    hipMemsetAsync(ws, 0, 512, stream);
    bel_main_kernel<<<NBLK, 256, 0, stream>>>(pred, target, ws, out);
}

// Round 4
// 122.695 us; speedup vs baseline: 1.3426x; 1.3426x over previous
//
#include <hip/hip_runtime.h>
#include <math.h>

#define BATCH 32
#define HH 512
#define WW 512
#define TH 16                  // output rows per block
#define HALO 2
#define SRH (TH + 2*HALO)      // 20 staged rows
#define NDW (WW / 4)           // 128 dwords per row (u8-packed)
#define CSTRIDE 132            // csum row stride in dwords (1 pad + 128 + 1 pad + 2 slack)
#define NPIX ((float)BATCH * HH * WW)
#define HW (HH * WW)
#define NBLK (BATCH * (HH / TH))   // 1024

// ws layout: 8 floats per block (6 used): [bid*8 + j]
// j: 0=ce 1=valid_cnt 2=focal 3=inter 4=sum_bp 5=sum_bt
// Non-atomic: every slot read by finalize is written every call (poison-safe).
// NOTE (round-3 post-mortem): do NOT fuse finalize via atomics/fence — the
// tail code flipped regalloc to VGPR=28, killed the batched prefetch (85us).

__global__ __launch_bounds__(256, 4) void bel_main_kernel(
        const float* __restrict__ pred,
        const int*   __restrict__ target,
        float*       __restrict__ ws) {
    __shared__ unsigned int t8[SRH][NDW];      // target, 1 byte/pixel
    __shared__ unsigned int csum[TH][CSTRIDE]; // vertical 5-sums, packed u8
    __shared__ float red[6][4];

    const int tid = threadIdx.x;
    const int bid = blockIdx.x;
    const int b   = bid >> 5;          // image
    const int ty  = bid & 31;          // row-tile
    const int y0  = ty * TH;
    const size_t tb = (size_t)b * HW;

    // zero the horizontal pad dwords of csum (left=0, right=NDW+1)
    if (tid < 2 * TH) {
        int rr = tid >> 1;
        csum[rr][(tid & 1) ? (NDW + 1) : 0] = 0u;
    }

    // ---- stage 20 rows of target as packed u8 (zero rows outside image) ----
    // Issued FIRST: oldest in the vmcnt FIFO, so the ds_writes below wait
    // only on these, not on the pred prefetch issued after.
    #pragma unroll
    for (int it = 0; it < (SRH * NDW) / 256; ++it) {   // 10 iters
        const int i  = tid + 256 * it;
        const int r  = i >> 7;
        const int c4 = i & 127;
        const int gy = y0 - HALO + r;
        unsigned int packed = 0u;
        if ((unsigned)gy < (unsigned)HH) {
            const int4 v = *(const int4*)(target + tb + ((size_t)gy << 9) + (c4 << 2));
            packed = (unsigned)v.x | ((unsigned)v.y << 8)
                   | ((unsigned)v.z << 16) | ((unsigned)v.w << 24);
        }
        t8[r][c4] = packed;
    }

    // ---- pred prefetch hoisted BEFORE the barriers: 16 float4 loads stay in
    // flight through staging + csum (one latency exposure instead of two).
    // Plain cached loads (round-1 lesson: nontemporal bypasses L3, inputs are
    // Infinity-Cache-resident in steady state — nt forced real HBM traffic).
    const float4* __restrict__ pr0 = (const float4*)(pred + tb * 2);
    const float4* __restrict__ pr1 = (const float4*)(pred + tb * 2 + HW);
    const int base4 = (y0 << 7) + tid;   // float4 index of this thread's slot 0

    float4 F0[8], F1[8];
    #pragma unroll
    for (int it = 0; it < 8; ++it) F0[it] = pr0[base4 + 256 * it];
    #pragma unroll
    for (int it = 0; it < 8; ++it) F1[it] = pr1[base4 + 256 * it];
    // Pin issue order: forbid the compiler from sinking the pred loads past
    // this point (round-3 failure mode: loads sank into the compute loop).
    asm volatile("" ::: "memory");

    __syncthreads();

    // ---- vertical 5-sum (packed u8 adds; max byte value 5, no carry) ----
    #pragma unroll
    for (int it = 0; it < (TH * NDW) / 256; ++it) {    // 8 iters
        const int j = tid + 256 * it;
        const int r = j >> 7;
        const int c = j & 127;
        csum[r][c + 1] = t8[r][c] + t8[r+1][c] + t8[r+2][c]
                       + t8[r+3][c] + t8[r+4][c];
    }
    __syncthreads();

    float ce_acc = 0.f, cnt_acc = 0.f, focal_acc = 0.f;
    float inter_acc = 0.f, bp_acc = 0.f, bt_acc = 0.f;

    const unsigned long long M5 = 0xFFFFFFFFFFull;      // 5 bytes
    const unsigned long long ALL5 = 0x0505050505ull;    // box sum == 25

    const int g  = tid & 127;          // loop-invariant column group
    const int rb = tid >> 7;           // 0 or 1

    #pragma unroll
    for (int it = 0; it < 8; ++it) {
        const int r = rb + 2 * it;

        const float4 f0 = F0[it];
        const float4 f1 = F1[it];

        const unsigned int L = csum[r][g];
        const unsigned int M = csum[r][g + 1];
        const unsigned int R = csum[r][g + 2];
        const unsigned int tdw = t8[r + HALO][g];

        const unsigned long long lo  = (unsigned long long)L | ((unsigned long long)M << 32);
        const unsigned long long mid = (unsigned long long)M | ((unsigned long long)R << 32);

        #pragma unroll
        for (int i = 0; i < 4; ++i) {
            unsigned long long w;
            if      (i == 0) w = (lo  >> 16) & M5;
            else if (i == 1) w = (lo  >> 24) & M5;
            else if (i == 2) w =  mid        & M5;
            else             w = (mid >>  8) & M5;
            const float bm = (w != 0ull && w != ALL5) ? 1.0f : 0.0f;

            const unsigned int tv = (tdw >> (8 * i)) & 0xFFu;

            const float p0 = (i == 0) ? f0.x : (i == 1) ? f0.y : (i == 2) ? f0.z : f0.w;
            const float p1 = (i == 0) ? f1.x : (i == 1) ? f1.y : (i == 2) ? f1.z : f1.w;

            const float d  = p1 - p0;
            const float e  = __expf(-fabsf(d));
            const float rz = 1.0f / (1.0f + e);
            const float pmin = e * rz;
            const float prob1 = (d >= 0.0f) ? rz : pmin;
            const float pt = tv ? prob1 : (1.0f - prob1);
            const float ce = -__logf(pt);

            const float valid = (tv != 250u) ? 1.0f : 0.0f;
            ce_acc  += ce * valid;
            cnt_acc += valid;

            const float omp = 1.0f - pt;
            focal_acc += omp * omp * ce;                // *0.25 folded at the end

            const float bp = prob1 * bm;
            const float bt = (float)tv * bm;
            inter_acc += bp * bt;
            bp_acc    += bp;
            bt_acc    += bt;
        }
    }

    // ---- block reduction ----
    float vals[6] = {ce_acc, cnt_acc, focal_acc * 0.25f, inter_acc, bp_acc, bt_acc};
    #pragma unroll
    for (int jj = 0; jj < 6; ++jj) {
        float v = vals[jj];
        #pragma unroll
        for (int off = 32; off > 0; off >>= 1)
            v += __shfl_down(v, off, 64);
        vals[jj] = v;
    }
    const int wave = tid >> 6;
    const int lane = tid & 63;
    if (lane == 0) {
        #pragma unroll
        for (int jj = 0; jj < 6; ++jj) red[jj][wave] = vals[jj];
    }
    __syncthreads();
    if (tid == 0) {
        float* p = ws + bid * 8;
        #pragma unroll
        for (int jj = 0; jj < 6; ++jj)
            p[jj] = red[jj][0] + red[jj][1] + red[jj][2] + red[jj][3];
    }
}

__global__ void bel_finalize_kernel(const float* __restrict__ ws,
                                    float* __restrict__ out) {
    __shared__ float simg[BATCH][4];
    const int t = threadIdx.x;          // 256 threads
    const int b = t >> 3;               // image 0..31
    const int s = t & 7;                // 8 lanes per image

    float a0 = 0.f, a1 = 0.f, a2 = 0.f, a3 = 0.f, a4 = 0.f, a5 = 0.f;
    #pragma unroll
    for (int k = 0; k < 4; ++k) {
        const int bid = (b << 5) + s + (k << 3);
        const float* p = ws + bid * 8;
        a0 += p[0]; a1 += p[1]; a2 += p[2];
        a3 += p[3]; a4 += p[4]; a5 += p[5];
    }
    #pragma unroll
    for (int off = 4; off > 0; off >>= 1) {
        a0 += __shfl_down(a0, off, 8);
        a1 += __shfl_down(a1, off, 8);
        a2 += __shfl_down(a2, off, 8);
        a3 += __shfl_down(a3, off, 8);
        a4 += __shfl_down(a4, off, 8);
        a5 += __shfl_down(a5, off, 8);
    }
    if (s == 0) {
        simg[b][0] = a0;
        simg[b][1] = a1;
        simg[b][2] = a2;
        simg[b][3] = 2.0f * a3 / (a4 + a5 + 1e-8f);   // dice_b
    }
    __syncthreads();
    if (t < BATCH) {
        float ce  = simg[t][0];
        float cnt = simg[t][1];
        float foc = simg[t][2];
        float dc  = simg[t][3];
        #pragma unroll
        for (int off = 16; off > 0; off >>= 1) {
            ce  += __shfl_down(ce,  off, 32);
            cnt += __shfl_down(cnt, off, 32);
            foc += __shfl_down(foc, off, 32);
            dc  += __shfl_down(dc,  off, 32);
        }
        if (t == 0) {
            const float ce_loss = ce / fmaxf(cnt, 1.0f);
            const float focal   = foc / NPIX;
            const float bdice   = 1.0f - dc / (float)BATCH;
            out[0] = ce_loss + focal + bdice;   // BOUNDARY_W = 1.0
        }
    }
}

extern "C" void kernel_launch(void* const* d_in, const int* in_sizes, int n_in,
                              void* d_out, int out_size, void* d_ws, size_t ws_size,
                              hipStream_t stream) {
    const float* pred   = (const float*)d_in[0];
    const int*   target = (const int*)d_in[1];
    float* ws  = (float*)d_ws;
    float* out = (float*)d_out;

    bel_main_kernel<<<NBLK, 256, 0, stream>>>(pred, target, ws);
    bel_finalize_kernel<<<1, 256, 0, stream>>>(ws, out);
}

// Round 5
// 117.780 us; speedup vs baseline: 1.3986x; 1.0417x over previous
//
#include <hip/hip_runtime.h>
#include <math.h>

#define BATCH 32
#define HH 512
#define WW 512
#define TH 16                  // output rows per block
#define HALO 2
#define SRH (TH + 2*HALO)      // 20 staged rows
#define NDW (WW / 4)           // 128 dwords per row (u8-packed)
#define CSTRIDE 132            // csum row stride in dwords (1 pad + 128 + 1 pad + 2 slack)
#define NPIX ((float)BATCH * HH * WW)
#define HW (HH * WW)
#define NBLK (BATCH * (HH / TH))   // 1024
#define NT 512                 // threads per block (8 waves)

// ws layout: 8 floats per block (6 used): [bid*8 + j]
// j: 0=ce 1=valid_cnt 2=focal 3=inter 4=sum_bp 5=sum_bt
// Non-atomic: every slot read by finalize is written every call (poison-safe).
//
// Round-3 post-mortem: fused atomic finalize flipped regalloc to VGPR=28 and
// killed the batched prefetch (85us). Round-1/4: hoisting the pred prefetch
// across the barriers always loses to the register allocator. This round:
// TLP instead of ILP — 512-thread blocks, 4 blocks/CU x 8 waves = 32 waves/CU
// (was 16), per-thread state halved so it fits the 64-VGPR cap of (512,8).

__global__ __launch_bounds__(NT, 8) void bel_main_kernel(
        const float* __restrict__ pred,
        const int*   __restrict__ target,
        float*       __restrict__ ws) {
    __shared__ unsigned int t8[SRH][NDW];      // target, 1 byte/pixel
    __shared__ unsigned int csum[TH][CSTRIDE]; // vertical 5-sums, packed u8
    __shared__ float red[6][8];

    const int tid = threadIdx.x;
    const int bid = blockIdx.x;
    const int b   = bid >> 5;          // image
    const int ty  = bid & 31;          // row-tile
    const int y0  = ty * TH;
    const size_t tb = (size_t)b * HW;

    // zero the horizontal pad dwords of csum (left=0, right=NDW+1)
    if (tid < 2 * TH) {
        int rr = tid >> 1;
        csum[rr][(tid & 1) ? (NDW + 1) : 0] = 0u;
    }

    // ---- stage 20 rows of target as packed u8 (zero rows outside image) ----
    #pragma unroll
    for (int it = 0; it < (SRH * NDW) / NT; ++it) {    // 5 iters
        const int i  = tid + NT * it;
        const int r  = i >> 7;
        const int c4 = i & 127;
        const int gy = y0 - HALO + r;
        unsigned int packed = 0u;
        if ((unsigned)gy < (unsigned)HH) {
            const int4 v = *(const int4*)(target + tb + ((size_t)gy << 9) + (c4 << 2));
            packed = (unsigned)v.x | ((unsigned)v.y << 8)
                   | ((unsigned)v.z << 16) | ((unsigned)v.w << 24);
        }
        t8[r][c4] = packed;
    }
    __syncthreads();

    // ---- vertical 5-sum (packed u8 adds; max byte value 5, no carry) ----
    #pragma unroll
    for (int it = 0; it < (TH * NDW) / NT; ++it) {     // 4 iters
        const int j = tid + NT * it;
        const int r = j >> 7;
        const int c = j & 127;
        csum[r][c + 1] = t8[r][c] + t8[r+1][c] + t8[r+2][c]
                       + t8[r+3][c] + t8[r+4][c];
    }
    __syncthreads();

    // ---- batched pred prefetch: 8 float4 loads in flight per thread ----
    // (after the barriers: staging registers are dead here — round-1/3/4
    //  post-mortems show hoisting across the barrier always spills/sinks)
    const float4* __restrict__ pr0 = (const float4*)(pred + tb * 2);
    const float4* __restrict__ pr1 = (const float4*)(pred + tb * 2 + HW);
    const int base4 = (y0 << 7) + tid;   // float4 index of this thread's slot 0

    float4 F0[4], F1[4];
    #pragma unroll
    for (int it = 0; it < 4; ++it) F0[it] = pr0[base4 + NT * it];
    #pragma unroll
    for (int it = 0; it < 4; ++it) F1[it] = pr1[base4 + NT * it];

    float ce_acc = 0.f, cnt_acc = 0.f, focal_acc = 0.f;
    float inter_acc = 0.f, bp_acc = 0.f, bt_acc = 0.f;

    const unsigned long long M5 = 0xFFFFFFFFFFull;      // 5 bytes
    const unsigned long long ALL5 = 0x0505050505ull;    // box sum == 25

    const int g  = tid & 127;          // loop-invariant column group
    const int rb = tid >> 7;           // 0..3

    #pragma unroll
    for (int it = 0; it < 4; ++it) {
        const int r = rb + 4 * it;

        const float4 f0 = F0[it];
        const float4 f1 = F1[it];

        const unsigned int L = csum[r][g];
        const unsigned int M = csum[r][g + 1];
        const unsigned int R = csum[r][g + 2];
        const unsigned int tdw = t8[r + HALO][g];

        const unsigned long long lo  = (unsigned long long)L | ((unsigned long long)M << 32);
        const unsigned long long mid = (unsigned long long)M | ((unsigned long long)R << 32);

        #pragma unroll
        for (int i = 0; i < 4; ++i) {
            unsigned long long w;
            if      (i == 0) w = (lo  >> 16) & M5;
            else if (i == 1) w = (lo  >> 24) & M5;
            else if (i == 2) w =  mid        & M5;
            else             w = (mid >>  8) & M5;
            const float bm = (w != 0ull && w != ALL5) ? 1.0f : 0.0f;

            const unsigned int tv = (tdw >> (8 * i)) & 0xFFu;

            const float p0 = (i == 0) ? f0.x : (i == 1) ? f0.y : (i == 2) ? f0.z : f0.w;
            const float p1 = (i == 0) ? f1.x : (i == 1) ? f1.y : (i == 2) ? f1.z : f1.w;

            const float d  = p1 - p0;
            const float e  = __expf(-fabsf(d));
            const float rz = 1.0f / (1.0f + e);
            const float pmin = e * rz;
            const float prob1 = (d >= 0.0f) ? rz : pmin;
            const float pt = tv ? prob1 : (1.0f - prob1);
            const float ce = -__logf(pt);

            const float valid = (tv != 250u) ? 1.0f : 0.0f;
            ce_acc  += ce * valid;
            cnt_acc += valid;

            const float omp = 1.0f - pt;
            focal_acc += omp * omp * ce;                // *0.25 folded at the end

            const float bp = prob1 * bm;
            const float bt = (float)tv * bm;
            inter_acc += bp * bt;
            bp_acc    += bp;
            bt_acc    += bt;
        }
    }

    // ---- block reduction (8 waves) ----
    float vals[6] = {ce_acc, cnt_acc, focal_acc * 0.25f, inter_acc, bp_acc, bt_acc};
    #pragma unroll
    for (int jj = 0; jj < 6; ++jj) {
        float v = vals[jj];
        #pragma unroll
        for (int off = 32; off > 0; off >>= 1)
            v += __shfl_down(v, off, 64);
        vals[jj] = v;
    }
    const int wave = tid >> 6;
    const int lane = tid & 63;
    if (lane == 0) {
        #pragma unroll
        for (int jj = 0; jj < 6; ++jj) red[jj][wave] = vals[jj];
    }
    __syncthreads();
    if (tid == 0) {
        float* p = ws + bid * 8;
        #pragma unroll
        for (int jj = 0; jj < 6; ++jj) {
            float s = 0.f;
            #pragma unroll
            for (int wv = 0; wv < 8; ++wv) s += red[jj][wv];
            p[jj] = s;
        }
    }
}

__global__ void bel_finalize_kernel(const float* __restrict__ ws,
                                    float* __restrict__ out) {
    __shared__ float simg[BATCH][4];
    const int t = threadIdx.x;          // 256 threads
    const int b = t >> 3;               // image 0..31
    const int s = t & 7;                // 8 lanes per image

    float a0 = 0.f, a1 = 0.f, a2 = 0.f, a3 = 0.f, a4 = 0.f, a5 = 0.f;
    #pragma unroll
    for (int k = 0; k < 4; ++k) {
        const int bid = (b << 5) + s + (k << 3);
        const float* p = ws + bid * 8;
        a0 += p[0]; a1 += p[1]; a2 += p[2];
        a3 += p[3]; a4 += p[4]; a5 += p[5];
    }
    #pragma unroll
    for (int off = 4; off > 0; off >>= 1) {
        a0 += __shfl_down(a0, off, 8);
        a1 += __shfl_down(a1, off, 8);
        a2 += __shfl_down(a2, off, 8);
        a3 += __shfl_down(a3, off, 8);
        a4 += __shfl_down(a4, off, 8);
        a5 += __shfl_down(a5, off, 8);
    }
    if (s == 0) {
        simg[b][0] = a0;
        simg[b][1] = a1;
        simg[b][2] = a2;
        simg[b][3] = 2.0f * a3 / (a4 + a5 + 1e-8f);   // dice_b
    }
    __syncthreads();
    if (t < BATCH) {
        float ce  = simg[t][0];
        float cnt = simg[t][1];
        float foc = simg[t][2];
        float dc  = simg[t][3];
        #pragma unroll
        for (int off = 16; off > 0; off >>= 1) {
            ce  += __shfl_down(ce,  off, 32);
            cnt += __shfl_down(cnt, off, 32);
            foc += __shfl_down(foc, off, 32);
            dc  += __shfl_down(dc,  off, 32);
        }
        if (t == 0) {
            const float ce_loss = ce / fmaxf(cnt, 1.0f);
            const float focal   = foc / NPIX;
            const float bdice   = 1.0f - dc / (float)BATCH;
            out[0] = ce_loss + focal + bdice;   // BOUNDARY_W = 1.0
        }
    }
}

extern "C" void kernel_launch(void* const* d_in, const int* in_sizes, int n_in,
                              void* d_out, int out_size, void* d_ws, size_t ws_size,
                              hipStream_t stream) {
    const float* pred   = (const float*)d_in[0];
    const int*   target = (const int*)d_in[1];
    float* ws  = (float*)d_ws;
    float* out = (float*)d_out;

    bel_main_kernel<<<NBLK, NT, 0, stream>>>(pred, target, ws);
    bel_finalize_kernel<<<1, 256, 0, stream>>>(ws, out);
}